// Round 10
// baseline (363.726 us; speedup 1.0000x reference)
//
#include <hip/hip_runtime.h>
#include <stdint.h>

#define NEUR 1024
#define BM 128            // rows per block
#define BN 512            // W2 output cols per block (2 blocks in N)
#define THREADS 512
#define H1S 1040          // h1 row stride bytes: 512 bf16 + 8 pad
#define L1S 80            // l1p row stride bytes: 40 shorts

typedef short  s16x8  __attribute__((ext_vector_type(8)));
typedef __bf16 bf16x8 __attribute__((ext_vector_type(8)));
typedef float  f32x16 __attribute__((ext_vector_type(16)));

__device__ __forceinline__ unsigned short f2bf(float f){
  unsigned u = __builtin_bit_cast(unsigned, f);
  u += 0x7FFFu + ((u >> 16) & 1u);          // round-to-nearest-even
  return (unsigned short)(u >> 16);
}
__device__ __forceinline__ float bf2f(unsigned short h){
  unsigned u = ((unsigned)h) << 16;
  return __builtin_bit_cast(float, u);
}
__device__ __forceinline__ f32x16 mfma32(bf16x8 a, bf16x8 b, f32x16 c){
  return __builtin_amdgcn_mfma_f32_32x32x16_bf16(a, b, c, 0, 0, 0);
}
__device__ __forceinline__ f32x16 zero16(){
  f32x16 v;
#pragma unroll
  for (int r = 0; r < 16; ++r) v[r] = 0.f;
  return v;
}
__device__ __forceinline__ bf16x8 ld16(const void* p){
  return __builtin_bit_cast(bf16x8, *reinterpret_cast<const s16x8*>(p));
}

// Pre-swizzle weights into MFMA-fragment order (coalesced GEMM loads).
// w2opt[((nt*64 + ks)*64 + l)*8 + j] = bf16(W2[nt*32 + (l&31)][ks*16 + (l>>5)*8 + j])
// w1opt[((nt*2  + ks)*64 + l)*8 + j] = bf16(W1 padded to K=32, same fragment map)
__global__ void prep_kernel(const float* __restrict__ W1, const float* __restrict__ W2,
                            unsigned short* __restrict__ w2opt, unsigned short* __restrict__ w1opt){
  const int nchunks = NEUR * 128;
  const int total = nchunks + 4096;
  for (int i = blockIdx.x*blockDim.x + threadIdx.x; i < total; i += gridDim.x*blockDim.x){
    if (i < nchunks){
      const int col = i >> 7, c8 = i & 127;
      const float* src = W2 + (size_t)col*NEUR + c8*8;
      const int ks = c8 >> 1, lf = c8 & 1, lane = lf*32 + (col & 31), nt = col >> 5;
      unsigned short* dst = w2opt + (((size_t)(nt*64 + ks)*64 + lane) * 8);
#pragma unroll
      for (int j = 0; j < 8; ++j) dst[j] = f2bf(src[j]);
    } else {
      const int o = i - nchunks;
      const int nt = o >> 7, ks = (o >> 6) & 1, lane = o & 63;
      const int col = nt*32 + (lane & 31);
      unsigned short* dst = w1opt + (size_t)o * 8;
#pragma unroll
      for (int j = 0; j < 8; ++j){
        const int k = ks*16 + (lane >> 5)*8 + j;
        dst[j] = (k < 10) ? f2bf(W1[col*10 + k]) : (unsigned short)0;
      }
    }
  }
}

// finish: out = sigmoid(partial[0] + partial[1] + b3)
__global__ void finish_kernel(const float* __restrict__ pws, const float* __restrict__ b3,
                              float* __restrict__ out, int batch){
  const int total = batch * 3;
  for (int i = blockIdx.x*blockDim.x + threadIdx.x; i < total; i += gridDim.x*blockDim.x){
    const int j = i - (i/3)*3;
    const float v = pws[i] + pws[(size_t)total + i] + b3[j];
    out[i] = 1.f / (1.f + __expf(-v));
  }
}

// Main fused kernel, BM=128 x BN=512 per block, K-split h1 (two halves of 512 neurons).
__global__ __launch_bounds__(THREADS, 2) void mlp_kernel(
    const float* __restrict__ x,
    const float* __restrict__ Wx, const float* __restrict__ bxp,
    const float* __restrict__ Wu, const float* __restrict__ bup,
    const float* __restrict__ b1, const float* __restrict__ b2,
    const float* __restrict__ W3,
    const unsigned short* __restrict__ w2opt, const unsigned short* __restrict__ w1opt,
    float* __restrict__ pws, int batch)
{
  extern __shared__ char smem[];
  char* l1p = smem;                 // [128][L1S] bf16-padded features (10240 B); later reused
  char* h1  = smem + BM*L1S;        // [128][H1S] current K-half of h1 (133120 B)

  const int tid = threadIdx.x;
  const int l   = tid & 63;
  const int wid = tid >> 6;         // 8 waves
  const int l31 = l & 31;
  const int lh  = l >> 5;
  const int wm  = wid >> 2;         // 0..1  (M group: rows wm*64..+64)
  const int wn  = wid & 3;          // 0..3  (N group: cols wn*128..+128 within BN)
  const int bm  = blockIdx.x >> 1;
  const int bn  = blockIdx.x & 1;
  const long rbase = (long)bm * BM;

  // ---- 1. stage x tile (128*25 f32) into h1 region
  float* xs = (float*)h1;
  for (int i = tid; i < BM*25; i += THREADS) xs[i] = x[rbase*25 + i];
  __syncthreads();

  // ---- 2. l1 features (f32 exact), bf16-pad to K=32
  if (tid < BM){
    const float* xr = xs + tid*25;
    float l1v[10];
#pragma unroll
    for (int g = 0; g < 3; ++g)
#pragma unroll
      for (int o = 0; o < 2; ++o){
        float s = bxp[o];
#pragma unroll
        for (int i = 0; i < 5; ++i) s += xr[g + 3*i] * Wx[o*5 + i];
        l1v[g*2 + o] = fmaxf(s, 0.f);
      }
#pragma unroll
    for (int g = 0; g < 2; ++g)
#pragma unroll
      for (int o = 0; o < 2; ++o){
        float s = bup[o];
#pragma unroll
        for (int i = 0; i < 5; ++i) s += xr[15 + g + 2*i] * Wu[o*5 + i];
        l1v[6 + g*2 + o] = fmaxf(s, 0.f);
      }
    unsigned short* dst = (unsigned short*)(l1p + tid*L1S);
#pragma unroll
    for (int i = 0; i < 10; ++i) dst[i] = f2bf(l1v[i]);
#pragma unroll
    for (int i = 10; i < 32; ++i) dst[i] = 0;
  }
  __syncthreads();

  // ---- persistent GEMM2 accumulators: wave tile 64 rows x 128 cols
  f32x16 acc[2][4];
#pragma unroll
  for (int mt = 0; mt < 2; ++mt)
#pragma unroll
    for (int nt = 0; nt < 4; ++nt) acc[mt][nt] = zero16();

  const int aBase = (wm*64 + l31)*H1S + lh*16;   // GEMM2 A base (bytes into h1)

  for (int h = 0; h < 2; ++h){
    // ---- 3. GEMM1 half h: h1[128][0..512) = relu(l1 @ W1[h*512..+512]^T + b1)
#pragma unroll
    for (int st = 0; st < 2; ++st){
      f32x16 c00 = zero16(), c01 = zero16(), c10 = zero16(), c11 = zero16();
      const int colh = st*256 + wn*64;           // col base within half
      const int ntg  = h*16 + st*8 + wn*2;       // global W1 fragment tile
#pragma unroll
      for (int ks = 0; ks < 2; ++ks){
        bf16x8 a0 = ld16(l1p + (wm*64 + l31)*L1S + ks*32 + lh*16);
        bf16x8 a1 = ld16(l1p + (wm*64 + 32 + l31)*L1S + ks*32 + lh*16);
        bf16x8 b0 = ld16(w1opt + (((size_t)(ntg + 0)*2 + ks)*64 + l) * 8);
        bf16x8 b1f= ld16(w1opt + (((size_t)(ntg + 1)*2 + ks)*64 + l) * 8);
        c00 = mfma32(a0, b0, c00);
        c10 = mfma32(a1, b0, c10);
        c01 = mfma32(a0, b1f, c01);
        c11 = mfma32(a1, b1f, c11);
      }
#pragma unroll
      for (int nt2 = 0; nt2 < 2; ++nt2){
        const int colHalf = colh + nt2*32 + l31;
        const float bv = b1[h*512 + colHalf];
        const f32x16& cA = nt2 ? c01 : c00;
        const f32x16& cB = nt2 ? c11 : c10;
#pragma unroll
        for (int r = 0; r < 16; ++r){
          const int rr = (r & 3) + 8*(r >> 2) + 4*lh;
          *reinterpret_cast<unsigned short*>(h1 + (wm*64 + rr)*H1S + colHalf*2) =
              f2bf(fmaxf(cA[r] + bv, 0.f));
          *reinterpret_cast<unsigned short*>(h1 + (wm*64 + 32 + rr)*H1S + colHalf*2) =
              f2bf(fmaxf(cB[r] + bv, 0.f));
        }
      }
    }
    __syncthreads();

    // ---- 4. GEMM2 K-half: 32 K-steps, MM4 pipeline (round-8 schedule)
    {
      const size_t hoff = (size_t)h * 32768;     // h*32 ks * 1024 B
      const char* pb0 = (const char*)w2opt + (((size_t)(bn*16 + wn*4 + 0)*64)*64 + l)*16 + hoff;
      const char* pb1 = (const char*)w2opt + (((size_t)(bn*16 + wn*4 + 1)*64)*64 + l)*16 + hoff;
      const char* pb2 = (const char*)w2opt + (((size_t)(bn*16 + wn*4 + 2)*64)*64 + l)*16 + hoff;
      const char* pb3 = (const char*)w2opt + (((size_t)(bn*16 + wn*4 + 3)*64)*64 + l)*16 + hoff;
      int ao = aBase;

      bf16x8 Aa0, Aa1, Ab0, Ab1;
      bf16x8 P0a, P0b, Q0a, Q0b, P1a, P1b, Q1a, Q1b;

#define MM4_01(A0_,A1_,B0_,B1_) do{ __builtin_amdgcn_s_setprio(1);            \
      acc[0][0]=mfma32(A0_,B0_,acc[0][0]); acc[1][0]=mfma32(A1_,B0_,acc[1][0]);\
      acc[0][1]=mfma32(A0_,B1_,acc[0][1]); acc[1][1]=mfma32(A1_,B1_,acc[1][1]);\
      __builtin_amdgcn_s_setprio(0); }while(0)
#define MM4_23(A0_,A1_,B0_,B1_) do{ __builtin_amdgcn_s_setprio(1);            \
      acc[0][2]=mfma32(A0_,B0_,acc[0][2]); acc[1][2]=mfma32(A1_,B0_,acc[1][2]);\
      acc[0][3]=mfma32(A0_,B1_,acc[0][3]); acc[1][3]=mfma32(A1_,B1_,acc[1][3]);\
      __builtin_amdgcn_s_setprio(0); }while(0)

      P0a = ld16(pb0);          P0b = ld16(pb1);
      Q0a = ld16(pb2);          Q0b = ld16(pb3);
      P1a = ld16(pb0 + 1024);   P1b = ld16(pb1 + 1024);
      Aa0 = ld16(h1 + ao);      Aa1 = ld16(h1 + ao + 32*H1S);

      for (int t = 0; t < 15; ++t){
        Q1a = ld16(pb2 + 1024);  Q1b = ld16(pb3 + 1024);
        Ab0 = ld16(h1 + ao + 32); Ab1 = ld16(h1 + ao + 32*H1S + 32);
        MM4_01(Aa0, Aa1, P0a, P0b);
        P0a = ld16(pb0 + 2048);  P0b = ld16(pb1 + 2048);
        MM4_23(Aa0, Aa1, Q0a, Q0b);
        Q0a = ld16(pb2 + 2048);  Q0b = ld16(pb3 + 2048);
        Aa0 = ld16(h1 + ao + 64); Aa1 = ld16(h1 + ao + 32*H1S + 64);
        MM4_01(Ab0, Ab1, P1a, P1b);
        P1a = ld16(pb0 + 3072);  P1b = ld16(pb1 + 3072);
        MM4_23(Ab0, Ab1, Q1a, Q1b);
        pb0 += 2048; pb1 += 2048; pb2 += 2048; pb3 += 2048; ao += 64;
      }
      // epilogue: ks=30,31
      Q1a = ld16(pb2 + 1024);  Q1b = ld16(pb3 + 1024);
      Ab0 = ld16(h1 + ao + 32); Ab1 = ld16(h1 + ao + 32*H1S + 32);
      MM4_01(Aa0, Aa1, P0a, P0b);
      MM4_23(Aa0, Aa1, Q0a, Q0b);
      MM4_01(Ab0, Ab1, P1a, P1b);
      MM4_23(Ab0, Ab1, Q1a, Q1b);
#undef MM4_01
#undef MM4_23
    }
    __syncthreads();   // done reading h1 (and l1p after h=1); next half may overwrite
  }

  // ---- 5. epilogue: h2 = relu(acc + b2); per-wave partial logits over its
  //         128 cols; lane-reduce over l31; stage in LDS [wn][128][3]; then
  //         cross-wn sum -> pws[bn]. (The missing inter-wave reduction.)
  float* sp = (float*)l1p;          // 4*128*3*4 = 6144 B, l1p is dead
  {
    float b2v[4], w30[4], w31[4], w32[4];
#pragma unroll
    for (int nt = 0; nt < 4; ++nt){
      const int colg = bn*512 + wn*128 + nt*32 + l31;
      b2v[nt] = b2[colg];
      w30[nt] = W3[0*NEUR + colg];
      w31[nt] = W3[1*NEUR + colg];
      w32[nt] = W3[2*NEUR + colg];
    }
#pragma unroll
    for (int mf = 0; mf < 2; ++mf){
      float p0[16], p1[16], p2[16];
#pragma unroll
      for (int r = 0; r < 16; ++r){ p0[r] = 0.f; p1[r] = 0.f; p2[r] = 0.f; }
#pragma unroll
      for (int nt = 0; nt < 4; ++nt)
#pragma unroll
        for (int r = 0; r < 16; ++r){
          const float hv = fmaxf(acc[mf][nt][r] + b2v[nt], 0.f);
          p0[r] += hv * w30[nt];
          p1[r] += hv * w31[nt];
          p2[r] += hv * w32[nt];
        }
#pragma unroll
      for (int off = 1; off < 32; off <<= 1)
#pragma unroll
        for (int r = 0; r < 16; ++r){
          p0[r] += __shfl_xor(p0[r], off, 64);
          p1[r] += __shfl_xor(p1[r], off, 64);
          p2[r] += __shfl_xor(p2[r], off, 64);
        }
      if (l31 == 0){
#pragma unroll
        for (int r = 0; r < 16; ++r){
          const int row = wm*64 + mf*32 + (r & 3) + 8*(r >> 2) + 4*lh;
          float* d = sp + ((size_t)wn*BM + row)*3;
          d[0] = p0[r]; d[1] = p1[r]; d[2] = p2[r];
        }
      }
    }
  }
  __syncthreads();

  for (int t2 = tid; t2 < BM*3; t2 += THREADS){
    const int row = t2 / 3, j = t2 - row*3;
    const float v = sp[(0*BM + row)*3 + j] + sp[(1*BM + row)*3 + j]
                  + sp[(2*BM + row)*3 + j] + sp[(3*BM + row)*3 + j];
    pws[((size_t)bn*batch + rbase + row)*3 + j] = v;
  }
}

// ---------- fallback (ws too small): round-8 kernel, direct W2 reads ----------
__global__ __launch_bounds__(THREADS, 2) void mlp_kernel_old(
    const float* __restrict__ x,
    const float* __restrict__ Wx, const float* __restrict__ bxp,
    const float* __restrict__ Wu, const float* __restrict__ bup,
    const float* __restrict__ W1, const float* __restrict__ b1,
    const float* __restrict__ W2f, const float* __restrict__ b2,
    const float* __restrict__ W3, const float* __restrict__ b3,
    float* __restrict__ out)
{
  extern __shared__ char smem[];
  unsigned short* l1p = (unsigned short*)smem;
  char* h1 = smem + 5120;   // 64 x 2064
  const int tid = threadIdx.x, l = tid & 63, wid = tid >> 6;
  const int l31 = l & 31, lh = l >> 5;
  const long rbase = (long)blockIdx.x * 64;

  float* xs = (float*)h1;
  for (int i = tid; i < 64*25; i += THREADS) xs[i] = x[rbase*25 + i];
  __syncthreads();
  if (tid < 64){
    const float* xr = xs + tid*25;
    float l1v[10];
#pragma unroll
    for (int g = 0; g < 3; ++g)
#pragma unroll
      for (int o = 0; o < 2; ++o){
        float s = bxp[o];
#pragma unroll
        for (int i = 0; i < 5; ++i) s += xr[g + 3*i] * Wx[o*5 + i];
        l1v[g*2 + o] = fmaxf(s, 0.f);
      }
#pragma unroll
    for (int g = 0; g < 2; ++g)
#pragma unroll
      for (int o = 0; o < 2; ++o){
        float s = bup[o];
#pragma unroll
        for (int i = 0; i < 5; ++i) s += xr[15 + g + 2*i] * Wu[o*5 + i];
        l1v[6 + g*2 + o] = fmaxf(s, 0.f);
      }
    unsigned short* dst = l1p + tid*40;
#pragma unroll
    for (int i = 0; i < 10; ++i) dst[i] = f2bf(l1v[i]);
#pragma unroll
    for (int i = 10; i < 32; ++i) dst[i] = 0;
  }
  __syncthreads();

  f32x16 c[2][4];
#pragma unroll
  for (int mt = 0; mt < 2; ++mt)
#pragma unroll
    for (int nt = 0; nt < 4; ++nt) c[mt][nt] = zero16();
#pragma unroll
  for (int ks = 0; ks < 2; ++ks){
    bf16x8 a0 = ld16(smem + l31*80 + ks*32 + lh*16);
    bf16x8 a1 = ld16(smem + (32 + l31)*80 + ks*32 + lh*16);
#pragma unroll
    for (int nt = 0; nt < 4; ++nt){
      const int col = wid*128 + nt*32 + l31;
      s16x8 raw;
#pragma unroll
      for (int j = 0; j < 8; ++j){
        const int k = ks*16 + lh*8 + j;
        raw[j] = (k < 10) ? (short)f2bf(W1[col*10 + k]) : (short)0;
      }
      bf16x8 b = __builtin_bit_cast(bf16x8, raw);
      c[0][nt] = mfma32(a0, b, c[0][nt]);
      c[1][nt] = mfma32(a1, b, c[1][nt]);
    }
  }
#pragma unroll
  for (int nt = 0; nt < 4; ++nt){
    const int col = wid*128 + nt*32 + l31;
    const float bv = b1[col];
#pragma unroll
    for (int mt = 0; mt < 2; ++mt)
#pragma unroll
      for (int r = 0; r < 16; ++r){
        const int row = mt*32 + (r & 3) + 8*(r >> 2) + 4*lh;
        *reinterpret_cast<unsigned short*>(h1 + row*2064 + col*2) =
            f2bf(fmaxf(c[mt][nt][r] + bv, 0.f));
      }
  }
  __syncthreads();

  f32x16 acc[2][4];
#pragma unroll
  for (int mt = 0; mt < 2; ++mt)
#pragma unroll
    for (int nt = 0; nt < 4; ++nt) acc[mt][nt] = zero16();
  const int aA0 = l31*2064 + lh*16;
  for (int ks = 0; ks < 64; ++ks){
    bf16x8 A0 = ld16(h1 + aA0 + ks*32);
    bf16x8 A1 = ld16(h1 + aA0 + 32*2064 + ks*32);
#pragma unroll
    for (int nt = 0; nt < 4; ++nt){
      const int col = wid*128 + nt*32 + l31;
      const float* p = W2f + (size_t)col*NEUR + ks*16 + lh*8;
      s16x8 raw;
#pragma unroll
      for (int j = 0; j < 8; ++j) raw[j] = (short)f2bf(p[j]);
      bf16x8 B = __builtin_bit_cast(bf16x8, raw);
      acc[0][nt] = mfma32(A0, B, acc[0][nt]);
      acc[1][nt] = mfma32(A1, B, acc[1][nt]);
    }
  }
  __syncthreads();
#pragma unroll
  for (int nt = 0; nt < 4; ++nt){
    const int col = wid*128 + nt*32 + l31;
    const float bv = b2[col];
#pragma unroll
    for (int mt = 0; mt < 2; ++mt)
#pragma unroll
      for (int r = 0; r < 16; ++r){
        const int row = mt*32 + (r & 3) + 8*(r >> 2) + 4*lh;
        *reinterpret_cast<unsigned short*>(h1 + row*2064 + col*2) =
            f2bf(fmaxf(acc[mt][nt][r] + bv, 0.f));
      }
  }
  __syncthreads();
  float s[8][3];
#pragma unroll
  for (int rr = 0; rr < 8; ++rr)
#pragma unroll
    for (int j = 0; j < 3; ++j) s[rr][j] = 0.f;
#pragma unroll
  for (int h = 0; h < 2; ++h){
    const int k0 = h*512 + l*8;
    float w3v[3][8];
#pragma unroll
    for (int j = 0; j < 3; ++j)
#pragma unroll
      for (int i = 0; i < 8; ++i) w3v[j][i] = W3[j*NEUR + k0 + i];
#pragma unroll
    for (int rr = 0; rr < 8; ++rr){
      const int row = wid*8 + rr;
      s16x8 raw = *reinterpret_cast<const s16x8*>(h1 + row*2064 + k0*2);
#pragma unroll
      for (int i = 0; i < 8; ++i){
        const float hv = bf2f((unsigned short)raw[i]);
        s[rr][0] += hv * w3v[0][i];
        s[rr][1] += hv * w3v[1][i];
        s[rr][2] += hv * w3v[2][i];
      }
    }
  }
#pragma unroll
  for (int off = 1; off < 64; off <<= 1)
#pragma unroll
    for (int rr = 0; rr < 8; ++rr)
#pragma unroll
      for (int j = 0; j < 3; ++j) s[rr][j] += __shfl_xor(s[rr][j], off, 64);
  if (l == 0){
#pragma unroll
    for (int rr = 0; rr < 8; ++rr){
      const int row = wid*8 + rr;
#pragma unroll
      for (int j = 0; j < 3; ++j)
        out[(rbase + row)*3 + j] = 1.f / (1.f + __expf(-(s[rr][j] + b3[j])));
    }
  }
}

extern "C" void kernel_launch(void* const* d_in, const int* in_sizes, int n_in,
                              void* d_out, int out_size, void* d_ws, size_t ws_size,
                              hipStream_t stream){
  const float* x  = (const float*)d_in[0];
  const float* Wx = (const float*)d_in[1];
  const float* bx = (const float*)d_in[2];
  const float* Wu = (const float*)d_in[3];
  const float* bu = (const float*)d_in[4];
  const float* W1 = (const float*)d_in[5];
  const float* b1 = (const float*)d_in[6];
  const float* W2 = (const float*)d_in[7];
  const float* b2 = (const float*)d_in[8];
  const float* W3 = (const float*)d_in[9];
  const float* b3 = (const float*)d_in[10];
  float* out = (float*)d_out;

  const int batch = in_sizes[0] / 25;
  const size_t w2_bytes  = (size_t)NEUR*NEUR*2;          // 2 MB
  const size_t w1_bytes  = (size_t)4096*8*2;             // 64 KB
  const size_t pws_bytes = (size_t)batch*3*2*4;          // 3.1 MB
  const size_t ws_need   = w2_bytes + w1_bytes + pws_bytes;

  if (ws_size >= ws_need && (batch % BM) == 0){
    unsigned short* w2opt = (unsigned short*)d_ws;
    unsigned short* w1opt = (unsigned short*)((char*)d_ws + w2_bytes);
    float* pws            = (float*)((char*)d_ws + w2_bytes + w1_bytes);

    prep_kernel<<<512, 256, 0, stream>>>(W1, W2, w2opt, w1opt);

    const int smem = BM*L1S + BM*H1S;   // 10240 + 133120 = 143360 B
    hipFuncSetAttribute(reinterpret_cast<const void*>(mlp_kernel),
                        hipFuncAttributeMaxDynamicSharedMemorySize, smem);
    const int nblocks = (batch / BM) * 2;
    mlp_kernel<<<nblocks, THREADS, smem, stream>>>(
        x, Wx, bx, Wu, bu, b1, b2, W3, w2opt, w1opt, pws, batch);

    finish_kernel<<<(batch*3 + 255)/256, 256, 0, stream>>>(pws, b3, out, batch);
  } else {
    const int smem = 5120 + 64*2064;
    hipFuncSetAttribute(reinterpret_cast<const void*>(mlp_kernel_old),
                        hipFuncAttributeMaxDynamicSharedMemorySize, smem);
    mlp_kernel_old<<<batch/64, THREADS, smem, stream>>>(
        x, Wx, bx, Wu, bu, W1, b1, W2, b2, W3, b3, out);
  }
}